// Round 1
// baseline (3449.130 us; speedup 1.0000x reference)
//
#include <hip/hip_runtime.h>

typedef unsigned int uint;
typedef unsigned short ushort;

typedef short short8 __attribute__((ext_vector_type(8)));
typedef float f32x4 __attribute__((ext_vector_type(4)));

#define DEV __device__ __forceinline__

DEV ushort f2bf(float x) {
    uint u = __float_as_uint(x);
    u += 0x7fffu + ((u >> 16) & 1u);
    return (ushort)(u >> 16);
}

// ---------------------------------------------------------------------------
// Generic direct conv: one thread per output pixel, OCB output channels per
// thread in registers. Input BN+ReLU (a,b fold) applied on load when BN=true.
// Weight indices are wave-uniform -> scalar loads (SMEM pipe, free vs VALU).
// ---------------------------------------------------------------------------
template <int IC, int OCT, int OCB, int K, int S, int P, int IH, int IW, int OH, int OW, bool BN>
__global__ __launch_bounds__(256) void convbn(
    const float* __restrict__ in, const float* __restrict__ w,
    const float* __restrict__ bias, const float* __restrict__ ab,
    float* __restrict__ out)
{
    constexpr int NPIX = OH * OW;
    int idx = blockIdx.x * 256 + threadIdx.x;
    if (idx >= 512 * NPIX) return;
    int ow = idx % OW;
    int oh = (idx / OW) % OH;
    int n  = idx / NPIX;
    int ocb = blockIdx.y * OCB;

    float acc[OCB];
#pragma unroll
    for (int o = 0; o < OCB; ++o) acc[o] = bias[ocb + o];

    const float* ip0 = in + (size_t)n * IC * IH * IW;
    for (int ic = 0; ic < IC; ++ic) {
        float aa = 0.f, bb = 0.f;
        if constexpr (BN) { aa = ab[ic]; bb = ab[IC + ic]; }
        const float* ip = ip0 + ic * (IH * IW);
        const float* wp = w + ((size_t)ocb * IC + ic) * (K * K);
#pragma unroll
        for (int kh = 0; kh < K; ++kh) {
            int ih = oh * S - P + kh;
            if (P > 0 && (uint)ih >= (uint)IH) continue;
#pragma unroll
            for (int kw = 0; kw < K; ++kw) {
                int iw = ow * S - P + kw;
                if (P > 0 && (uint)iw >= (uint)IW) continue;
                float v = ip[ih * IW + iw];
                if constexpr (BN) v = fmaxf(fmaf(aa, v, bb), 0.f);
#pragma unroll
                for (int o = 0; o < OCB; ++o)
                    acc[o] = fmaf(v, wp[o * IC * K * K + kh * K + kw], acc[o]);
            }
        }
    }
    float* op = out + ((size_t)n * OCT + ocb) * NPIX + oh * OW + ow;
#pragma unroll
    for (int o = 0; o < OCB; ++o) op[(size_t)o * NPIX] = acc[o];
}

// ---------------------------------------------------------------------------
// Per-channel sum/sumsq over (N,H,W). Grid = C*64 blocks; block = (c, 8 images).
// sums layout per layer: sum at [c], sumsq at [128+c].
// ---------------------------------------------------------------------------
template <int C, int HW>
__global__ __launch_bounds__(256) void bnstats(const float* __restrict__ y,
                                               float* __restrict__ sums)
{
    int c  = blockIdx.x >> 6;
    int nb = blockIdx.x & 63;
    float s = 0.f, q = 0.f;
    for (int n = nb * 8; n < nb * 8 + 8; ++n) {
        const float* p = y + ((size_t)n * C + c) * HW;
        for (int i = threadIdx.x; i < HW; i += 256) {
            float v = p[i];
            s += v;
            q = fmaf(v, v, q);
        }
    }
    for (int off = 32; off; off >>= 1) {
        s += __shfl_down(s, off);
        q += __shfl_down(q, off);
    }
    __shared__ float ls[4], lq[4];
    int lane = threadIdx.x & 63, wv = threadIdx.x >> 6;
    if (lane == 0) { ls[wv] = s; lq[wv] = q; }
    __syncthreads();
    if (threadIdx.x == 0) {
        s = ls[0] + ls[1] + ls[2] + ls[3];
        q = lq[0] + lq[1] + lq[2] + lq[3];
        atomicAdd(&sums[c], s);
        atomicAdd(&sums[128 + c], q);
    }
}

// sums -> (a, b) fold:  h = relu(a*y + b)
__global__ __launch_bounds__(128) void mkab(const float* __restrict__ sums,
                                            const float* __restrict__ g,
                                            const float* __restrict__ be,
                                            float* __restrict__ ab, int C, float invP)
{
    int c = threadIdx.x;
    if (c >= C) return;
    float mu  = sums[c] * invP;
    float var = fmaf(-mu, mu, sums[128 + c] * invP);
    float a   = g[c] / sqrtf(var + 1e-5f);
    ab[c]     = a;
    ab[C + c] = fmaf(-mu, a, be[c]);
}

// Global average pool with BN4+ReLU applied. One wave per (n,c).
__global__ __launch_bounds__(64) void pool(const float* __restrict__ y,
                                           const float* __restrict__ ab,
                                           float* __restrict__ f)
{
    int b = blockIdx.x;
    int c = b & 127;
    int n = b >> 7;
    const float* p = y + ((size_t)n * 128 + c) * 576;
    float aa = ab[c], bb = ab[128 + c];
    float s = 0.f;
    for (int i = threadIdx.x; i < 576; i += 64)
        s += fmaxf(fmaf(aa, p[i], bb), 0.f);
    for (int off = 32; off; off >>= 1) s += __shfl_down(s, off);
    if (threadIdx.x == 0) f[n * 128 + c] = s * (1.f / 576.f);
}

// L2-normalize feature rows, emit bf16.
__global__ __launch_bounds__(128) void fnorm(const float* __restrict__ f,
                                             ushort* __restrict__ fnb)
{
    int n = blockIdx.x, t = threadIdx.x;
    float v = f[n * 128 + t];
    float q = v * v;
    for (int off = 32; off; off >>= 1) q += __shfl_down(q, off);
    __shared__ float l[2];
    if ((t & 63) == 0) l[t >> 6] = q;
    __syncthreads();
    float inv = 1.f / fmaxf(sqrtf(l[0] + l[1]), 1e-12f);
    fnb[n * 128 + t] = f2bf(v * inv);
}

// arc_w row inverse norms. One wave per row.
__global__ __launch_bounds__(256) void wnorm(const float* __restrict__ w,
                                             float* __restrict__ winv)
{
    int wv = threadIdx.x >> 6, lane = threadIdx.x & 63;
    int j = blockIdx.x * 4 + wv;
    const float* p = w + (size_t)j * 128;
    float v0 = p[lane], v1 = p[lane + 64];
    float q = fmaf(v0, v0, v1 * v1);
    for (int off = 32; off; off >>= 1) q += __shfl_down(q, off);
    if (lane == 0) winv[j] = 1.f / fmaxf(sqrtf(q), 1e-12f);
}

// ---------------------------------------------------------------------------
// Final GEMM: out[i][j] = 64 * (fn[i] . wn[j]), margin fix at j == gt[i].
// M=512, N=100000, K=128. bf16 MFMA 16x16x32, fp32 accumulate.
// Block = 4 waves; wave owns 16 N-cols; B frags (w row * winv, bf16) live in
// registers for the whole M loop; A frags streamed from the 128 KB fnb table.
// ---------------------------------------------------------------------------
__global__ __launch_bounds__(256) void arc_gemm(const ushort* __restrict__ fnb,
                                                const float* __restrict__ aw,
                                                const float* __restrict__ winv,
                                                const int* __restrict__ gt,
                                                float* __restrict__ out)
{
    const int lane = threadIdx.x & 63, wv = threadIdx.x >> 6;
    const int col = lane & 15, quad = lane >> 4;
    const int j = blockIdx.x * 64 + wv * 16 + col;
    const bool jvalid = (j < 100000);
    const int jc = jvalid ? j : 99999;

    const float wi = winv[jc];
    const float* wp = aw + (size_t)jc * 128 + quad * 8;
    short8 bfr[4];
#pragma unroll
    for (int s = 0; s < 4; ++s) {
        short8 t;
#pragma unroll
        for (int e = 0; e < 8; ++e) t[e] = (short)f2bf(wp[s * 32 + e] * wi);
        bfr[s] = t;
    }

    const float cm = 0.87758256189037272f;  // cos(0.5)
    const float sm = 0.47942553860420301f;  // sin(0.5)

    for (int mt = 0; mt < 32; ++mt) {
        const ushort* ap = fnb + (size_t)(mt * 16 + col) * 128 + quad * 8;
        f32x4 acc = {0.f, 0.f, 0.f, 0.f};
#pragma unroll
        for (int s = 0; s < 4; ++s) {
            short8 af;
            __builtin_memcpy(&af, ap + s * 32, 16);
            acc = __builtin_amdgcn_mfma_f32_16x16x32_bf16(af, bfr[s], acc, 0, 0, 0);
        }
#pragma unroll
        for (int r = 0; r < 4; ++r) {
            int row = mt * 16 + quad * 4 + r;
            float v = acc[r];
            float o = 64.f * v;
            if (gt[row] == j) {
                float t = fmaxf(1.f - v * v, 0.f);
                o = 64.f * fmaf(v, cm, -sqrtf(t) * sm);
            }
            if (jvalid) out[(size_t)row * 100000 + j] = o;
        }
    }
}

// ---------------------------------------------------------------------------
extern "C" void kernel_launch(void* const* d_in, const int* in_sizes, int n_in,
                              void* d_out, int out_size, void* d_ws, size_t ws_size,
                              hipStream_t stream)
{
    const float* x   = (const float*)d_in[0];
    const int*   gt  = (const int*)d_in[1];
    const float* w1  = (const float*)d_in[2];
    const float* b1  = (const float*)d_in[3];
    const float* g1  = (const float*)d_in[4];
    const float* be1 = (const float*)d_in[5];
    const float* w2  = (const float*)d_in[6];
    const float* b2  = (const float*)d_in[7];
    const float* g2  = (const float*)d_in[8];
    const float* be2 = (const float*)d_in[9];
    const float* w3  = (const float*)d_in[10];
    const float* b3  = (const float*)d_in[11];
    const float* g3  = (const float*)d_in[12];
    const float* be3 = (const float*)d_in[13];
    const float* w4  = (const float*)d_in[14];
    const float* b4  = (const float*)d_in[15];
    const float* g4  = (const float*)d_in[16];
    const float* be4 = (const float*)d_in[17];
    const float* aw  = (const float*)d_in[18];
    float* out = (float*)d_out;

    float* ws = (float*)d_ws;
    float* bufA = ws;                    // 25,690,112 floats (y1, then y3)
    float* bufB = ws + 25690112;         // 37,748,736 floats (y2, then y4)
    float* sums = ws + 63438848;         // 4 layers x 256
    float* ab   = ws + 63439872;         // 4 layers x 256
    float* fbuf = ws + 63440896;         // 512*128
    ushort* fnb = (ushort*)(ws + 63506432); // 512*128 bf16
    float* wiv  = ws + 63539200;         // 100,000

    hipMemsetAsync(sums, 0, 1024 * sizeof(float), stream);

    // conv1: (512,1,112,112) -> (512,16,56,56), 4x4 s2 p1, no input BN
    convbn<1, 16, 16, 4, 2, 1, 112, 112, 56, 56, false>
        <<<6272, 256, 0, stream>>>(x, w1, b1, nullptr, bufA);
    bnstats<16, 3136><<<16 * 64, 256, 0, stream>>>(bufA, sums);
    mkab<<<1, 128, 0, stream>>>(sums, g1, be1, ab, 16, 1.f / 1605632.f);

    // conv2: -> (512,32,28,28), 4x4 s2 p1
    convbn<16, 32, 32, 4, 2, 1, 56, 56, 28, 28, true>
        <<<1568, 256, 0, stream>>>(bufA, w2, b2, ab, bufB);
    bnstats<32, 784><<<32 * 64, 256, 0, stream>>>(bufB, sums + 256);
    mkab<<<1, 128, 0, stream>>>(sums + 256, g2, be2, ab + 256, 32, 1.f / 401408.f);

    // conv3: -> (512,64,26,26), 3x3 s1 p0
    convbn<32, 64, 64, 3, 1, 0, 28, 28, 26, 26, true>
        <<<1352, 256, 0, stream>>>(bufB, w3, b3, ab + 256, bufA);
    bnstats<64, 676><<<64 * 64, 256, 0, stream>>>(bufA, sums + 512);
    mkab<<<1, 128, 0, stream>>>(sums + 512, g3, be3, ab + 512, 64, 1.f / 346112.f);

    // conv4: -> (512,128,24,24), 3x3 s1 p0, 64 oc per thread, 2 oc-halves
    convbn<64, 128, 64, 3, 1, 0, 26, 26, 24, 24, true>
        <<<dim3(1152, 2), 256, 0, stream>>>(bufA, w4, b4, ab + 512, bufB);
    bnstats<128, 576><<<128 * 64, 256, 0, stream>>>(bufB, sums + 768);
    mkab<<<1, 128, 0, stream>>>(sums + 768, g4, be4, ab + 768, 128, 1.f / 294912.f);

    // pool + feature normalize (bf16)
    pool<<<65536, 64, 0, stream>>>(bufB, ab + 768, fbuf);
    fnorm<<<512, 128, 0, stream>>>(fbuf, fnb);

    // arc_w row norms
    wnorm<<<25000, 256, 0, stream>>>(aw, wiv);

    // cosine logits + margin + scale
    arc_gemm<<<1563, 256, 0, stream>>>(fnb, aw, wiv, gt, out);
}

// Round 2
// 2304.789 us; speedup vs baseline: 1.4965x; 1.4965x over previous
//
#include <hip/hip_runtime.h>

typedef unsigned int uint;
typedef unsigned short ushort;

typedef short short8 __attribute__((ext_vector_type(8)));
typedef float f32x4 __attribute__((ext_vector_type(4)));

#define DEV __device__ __forceinline__

DEV ushort f2bf(float x) {
    uint u = __float_as_uint(x);
    u += 0x7fffu + ((u >> 16) & 1u);
    return (ushort)(u >> 16);
}

// ---------------------------------------------------------------------------
// Direct conv + fused BN-stats. One thread per output pixel, OCB output
// channels per thread in VGPR accumulators (OCB<=32 so they stay in VGPRs —
// OCB=64 made the compiler evict acc[] to AGPRs: 3 instr/FMA, 2008us conv4).
// Input BN+ReLU (a,b fold) applied on load when BN=true. Weight indices are
// wave-uniform -> scalar loads. Epilogue: per-channel sum/sumsq shfl-reduce
// -> LDS -> one atomic per block per channel into 8 contention slots.
// Grids divide exactly (512*OH*OW % 256 == 0 for all layers): no bounds check.
// ---------------------------------------------------------------------------
template <int IC, int OCT, int OCB, int K, int S, int P, int IH, int IW, int OH, int OW, bool BN>
__global__ __launch_bounds__(256, 2) void convbn(
    const float* __restrict__ in, const float* __restrict__ w,
    const float* __restrict__ bias, const float* __restrict__ ab,
    float* __restrict__ out, float* __restrict__ sums)
{
    constexpr int NPIX = OH * OW;
    int idx = blockIdx.x * 256 + threadIdx.x;
    int ow = idx % OW;
    int oh = (idx / OW) % OH;
    int n  = idx / NPIX;
    int ocb = blockIdx.y * OCB;

    float acc[OCB];
#pragma unroll
    for (int o = 0; o < OCB; ++o) acc[o] = bias[ocb + o];

    const float* ip0 = in + (size_t)n * IC * IH * IW;
    for (int ic = 0; ic < IC; ++ic) {
        float aa = 0.f, bb = 0.f;
        if constexpr (BN) { aa = ab[ic]; bb = ab[IC + ic]; }
        const float* ip = ip0 + ic * (IH * IW);
        const float* wp = w + ((size_t)ocb * IC + ic) * (K * K);
#pragma unroll
        for (int kh = 0; kh < K; ++kh) {
            int ih = oh * S - P + kh;
            if (P > 0 && (uint)ih >= (uint)IH) continue;
#pragma unroll
            for (int kw = 0; kw < K; ++kw) {
                int iw = ow * S - P + kw;
                if (P > 0 && (uint)iw >= (uint)IW) continue;
                float v = ip[ih * IW + iw];
                if constexpr (BN) v = fmaxf(fmaf(aa, v, bb), 0.f);
#pragma unroll
                for (int o = 0; o < OCB; ++o)
                    acc[o] = fmaf(v, wp[o * IC * K * K + kh * K + kw], acc[o]);
            }
        }
    }

    float* op = out + ((size_t)n * OCT + ocb) * NPIX + oh * OW + ow;
#pragma unroll
    for (int o = 0; o < OCB; ++o) op[(size_t)o * NPIX] = acc[o];

    // ---- fused BN stats ----
    __shared__ float red[2][4][OCB];
    int lane = threadIdx.x & 63, wv = threadIdx.x >> 6;
#pragma unroll
    for (int o = 0; o < OCB; ++o) {
        float s = acc[o], q = acc[o] * acc[o];
#pragma unroll
        for (int off = 32; off; off >>= 1) {
            s += __shfl_down(s, off);
            q += __shfl_down(q, off);
        }
        if (lane == 0) { red[0][wv][o] = s; red[1][wv][o] = q; }
    }
    __syncthreads();
    float* sl = sums + (blockIdx.x & 7) * 256;
    int t = threadIdx.x;
    if (t < OCB)
        atomicAdd(&sl[ocb + t], red[0][0][t] + red[0][1][t] + red[0][2][t] + red[0][3][t]);
    else if (t >= 64 && t < 64 + OCB) {
        int o = t - 64;
        atomicAdd(&sl[128 + ocb + o], red[1][0][o] + red[1][1][o] + red[1][2][o] + red[1][3][o]);
    }
}

// sums (8 slots x 256) -> (a, b) fold:  h = relu(a*y + b)
__global__ __launch_bounds__(128) void mkab(const float* __restrict__ sums,
                                            const float* __restrict__ g,
                                            const float* __restrict__ be,
                                            float* __restrict__ ab, int C, float invP)
{
    int c = threadIdx.x;
    if (c >= C) return;
    float s = 0.f, q = 0.f;
#pragma unroll
    for (int k = 0; k < 8; ++k) { s += sums[k * 256 + c]; q += sums[k * 256 + 128 + c]; }
    float mu  = s * invP;
    float var = fmaf(-mu, mu, q * invP);
    float a   = g[c] / sqrtf(var + 1e-5f);
    ab[c]     = a;
    ab[C + c] = fmaf(-mu, a, be[c]);
}

// Global average pool with BN4+ReLU applied. One wave per (n,c).
__global__ __launch_bounds__(64) void pool(const float* __restrict__ y,
                                           const float* __restrict__ ab,
                                           float* __restrict__ f)
{
    int b = blockIdx.x;
    int c = b & 127;
    int n = b >> 7;
    const float* p = y + ((size_t)n * 128 + c) * 576;
    float aa = ab[c], bb = ab[128 + c];
    float s = 0.f;
    for (int i = threadIdx.x; i < 576; i += 64)
        s += fmaxf(fmaf(aa, p[i], bb), 0.f);
    for (int off = 32; off; off >>= 1) s += __shfl_down(s, off);
    if (threadIdx.x == 0) f[n * 128 + c] = s * (1.f / 576.f);
}

// L2-normalize feature rows, emit bf16.
__global__ __launch_bounds__(128) void fnorm(const float* __restrict__ f,
                                             ushort* __restrict__ fnb)
{
    int n = blockIdx.x, t = threadIdx.x;
    float v = f[n * 128 + t];
    float q = v * v;
    for (int off = 32; off; off >>= 1) q += __shfl_down(q, off);
    __shared__ float l[2];
    if ((t & 63) == 0) l[t >> 6] = q;
    __syncthreads();
    float inv = 1.f / fmaxf(sqrtf(l[0] + l[1]), 1e-12f);
    fnb[n * 128 + t] = f2bf(v * inv);
}

// arc_w row inverse norms. One wave per row.
__global__ __launch_bounds__(256) void wnorm(const float* __restrict__ w,
                                             float* __restrict__ winv)
{
    int wv = threadIdx.x >> 6, lane = threadIdx.x & 63;
    int j = blockIdx.x * 4 + wv;
    const float* p = w + (size_t)j * 128;
    float v0 = p[lane], v1 = p[lane + 64];
    float q = fmaf(v0, v0, v1 * v1);
    for (int off = 32; off; off >>= 1) q += __shfl_down(q, off);
    if (lane == 0) winv[j] = 1.f / fmaxf(sqrtf(q), 1e-12f);
}

// ---------------------------------------------------------------------------
// Final GEMM: out[i][j] = 64 * (fn[i] . wn[j]), margin fix at j == gt[i].
// M=512, N=100000, K=128. bf16 MFMA 16x16x32, fp32 accumulate.
// ---------------------------------------------------------------------------
__global__ __launch_bounds__(256) void arc_gemm(const ushort* __restrict__ fnb,
                                                const float* __restrict__ aw,
                                                const float* __restrict__ winv,
                                                const int* __restrict__ gt,
                                                float* __restrict__ out)
{
    const int lane = threadIdx.x & 63, wv = threadIdx.x >> 6;
    const int col = lane & 15, quad = lane >> 4;
    const int j = blockIdx.x * 64 + wv * 16 + col;
    const bool jvalid = (j < 100000);
    const int jc = jvalid ? j : 99999;

    const float wi = winv[jc];
    const float* wp = aw + (size_t)jc * 128 + quad * 8;
    short8 bfr[4];
#pragma unroll
    for (int s = 0; s < 4; ++s) {
        short8 t;
#pragma unroll
        for (int e = 0; e < 8; ++e) t[e] = (short)f2bf(wp[s * 32 + e] * wi);
        bfr[s] = t;
    }

    const float cm = 0.87758256189037272f;  // cos(0.5)
    const float sm = 0.47942553860420301f;  // sin(0.5)

    for (int mt = 0; mt < 32; ++mt) {
        const ushort* ap = fnb + (size_t)(mt * 16 + col) * 128 + quad * 8;
        f32x4 acc = {0.f, 0.f, 0.f, 0.f};
#pragma unroll
        for (int s = 0; s < 4; ++s) {
            short8 af;
            __builtin_memcpy(&af, ap + s * 32, 16);
            acc = __builtin_amdgcn_mfma_f32_16x16x32_bf16(af, bfr[s], acc, 0, 0, 0);
        }
#pragma unroll
        for (int r = 0; r < 4; ++r) {
            int row = mt * 16 + quad * 4 + r;
            float v = acc[r];
            float o = 64.f * v;
            if (gt[row] == j) {
                float t = fmaxf(1.f - v * v, 0.f);
                o = 64.f * fmaf(v, cm, -sqrtf(t) * sm);
            }
            if (jvalid) out[(size_t)row * 100000 + j] = o;
        }
    }
}

// ---------------------------------------------------------------------------
extern "C" void kernel_launch(void* const* d_in, const int* in_sizes, int n_in,
                              void* d_out, int out_size, void* d_ws, size_t ws_size,
                              hipStream_t stream)
{
    const float* x   = (const float*)d_in[0];
    const int*   gt  = (const int*)d_in[1];
    const float* w1  = (const float*)d_in[2];
    const float* b1  = (const float*)d_in[3];
    const float* g1  = (const float*)d_in[4];
    const float* be1 = (const float*)d_in[5];
    const float* w2  = (const float*)d_in[6];
    const float* b2  = (const float*)d_in[7];
    const float* g2  = (const float*)d_in[8];
    const float* be2 = (const float*)d_in[9];
    const float* w3  = (const float*)d_in[10];
    const float* b3  = (const float*)d_in[11];
    const float* g3  = (const float*)d_in[12];
    const float* be3 = (const float*)d_in[13];
    const float* w4  = (const float*)d_in[14];
    const float* b4  = (const float*)d_in[15];
    const float* g4  = (const float*)d_in[16];
    const float* be4 = (const float*)d_in[17];
    const float* aw  = (const float*)d_in[18];
    float* out = (float*)d_out;

    float* ws = (float*)d_ws;
    float* bufA = ws;                        // 25,690,112 floats (y1, then y3)
    float* bufB = ws + 25690112;             // 37,748,736 floats (y2, then y4)
    float* sums = ws + 63438848;             // 4 layers x 8 slots x 256
    float* ab   = ws + 63447040;             // 4 layers x 256
    float* fbuf = ws + 63448064;             // 512*128
    ushort* fnb = (ushort*)(ws + 63513600);  // 512*128 bf16 (32768 floats)
    float* wiv  = ws + 63546368;             // 100,000

    hipMemsetAsync(sums, 0, 4 * 2048 * sizeof(float), stream);

    // conv1: (512,1,112,112) -> (512,16,56,56), 4x4 s2 p1, no input BN
    convbn<1, 16, 16, 4, 2, 1, 112, 112, 56, 56, false>
        <<<6272, 256, 0, stream>>>(x, w1, b1, nullptr, bufA, sums);
    mkab<<<1, 128, 0, stream>>>(sums, g1, be1, ab, 16, 1.f / 1605632.f);

    // conv2: -> (512,32,28,28), 4x4 s2 p1
    convbn<16, 32, 32, 4, 2, 1, 56, 56, 28, 28, true>
        <<<1568, 256, 0, stream>>>(bufA, w2, b2, ab, bufB, sums + 2048);
    mkab<<<1, 128, 0, stream>>>(sums + 2048, g2, be2, ab + 256, 32, 1.f / 401408.f);

    // conv3: -> (512,64,26,26), 3x3 s1 p0, 32 oc/thread x 2 blocks
    convbn<32, 64, 32, 3, 1, 0, 28, 28, 26, 26, true>
        <<<dim3(1352, 2), 256, 0, stream>>>(bufB, w3, b3, ab + 256, bufA, sums + 4096);
    mkab<<<1, 128, 0, stream>>>(sums + 4096, g3, be3, ab + 512, 64, 1.f / 346112.f);

    // conv4: -> (512,128,24,24), 3x3 s1 p0, 32 oc/thread x 4 blocks
    convbn<64, 128, 32, 3, 1, 0, 26, 26, 24, 24, true>
        <<<dim3(1152, 4), 256, 0, stream>>>(bufA, w4, b4, ab + 512, bufB, sums + 6144);
    mkab<<<1, 128, 0, stream>>>(sums + 6144, g4, be4, ab + 768, 128, 1.f / 294912.f);

    // pool + feature normalize (bf16)
    pool<<<65536, 64, 0, stream>>>(bufB, ab + 768, fbuf);
    fnorm<<<512, 128, 0, stream>>>(fbuf, fnb);

    // arc_w row norms
    wnorm<<<25000, 256, 0, stream>>>(aw, wiv);

    // cosine logits + margin + scale
    arc_gemm<<<1563, 256, 0, stream>>>(fnb, aw, wiv, gt, out);
}

// Round 3
// 780.229 us; speedup vs baseline: 4.4207x; 2.9540x over previous
//
#include <hip/hip_runtime.h>

typedef unsigned int uint;
typedef unsigned short ushort;

typedef _Float16 half8 __attribute__((ext_vector_type(8)));
typedef float f32x4 __attribute__((ext_vector_type(4)));

#define DEV __device__ __forceinline__

DEV ushort f2h(float x) {
    _Float16 h = (_Float16)x;
    ushort u;
    __builtin_memcpy(&u, &h, 2);
    return u;
}

// ---------------------------------------------------------------------------
// conv1: direct fp32 VALU (IC=1, K too small for MFMA). One thread per output
// pixel, 16 oc in registers. Output y1: NHWC f16. Fused BN stats.
// ---------------------------------------------------------------------------
__global__ __launch_bounds__(256, 2) void conv1_k(
    const float* __restrict__ x, const float* __restrict__ w,
    const float* __restrict__ bias, ushort* __restrict__ y1,
    float* __restrict__ sums)
{
    int idx = blockIdx.x * 256 + threadIdx.x;
    int ow = idx % 56;
    int oh = (idx / 56) % 56;
    int n  = idx / 3136;

    float acc[16];
#pragma unroll
    for (int o = 0; o < 16; ++o) acc[o] = bias[o];

    const float* xp = x + (size_t)n * 12544;
#pragma unroll
    for (int kh = 0; kh < 4; ++kh) {
        int ih = oh * 2 - 1 + kh;
        if ((uint)ih >= 112u) continue;
#pragma unroll
        for (int kw = 0; kw < 4; ++kw) {
            int iw = ow * 2 - 1 + kw;
            if ((uint)iw >= 112u) continue;
            float v = xp[ih * 112 + iw];
#pragma unroll
            for (int o = 0; o < 16; ++o)
                acc[o] = fmaf(v, w[o * 16 + kh * 4 + kw], acc[o]);
        }
    }

    ushort hs[16];
#pragma unroll
    for (int o = 0; o < 16; ++o) hs[o] = f2h(acc[o]);
    __builtin_memcpy(y1 + (size_t)idx * 16, hs, 32);

    // fused BN stats
    __shared__ float red[2][4][16];
    int lane = threadIdx.x & 63, wv = threadIdx.x >> 6;
#pragma unroll
    for (int o = 0; o < 16; ++o) {
        float s = acc[o], q = acc[o] * acc[o];
#pragma unroll
        for (int off = 32; off; off >>= 1) {
            s += __shfl_down(s, off);
            q += __shfl_down(q, off);
        }
        if (lane == 0) { red[0][wv][o] = s; red[1][wv][o] = q; }
    }
    __syncthreads();
    float* sl = sums + (blockIdx.x & 7) * 256;
    int t = threadIdx.x;
    if (t < 16)
        atomicAdd(&sl[t], red[0][0][t] + red[0][1][t] + red[0][2][t] + red[0][3][t]);
    else if (t >= 64 && t < 80) {
        int o = t - 64;
        atomicAdd(&sl[128 + o], red[1][0][o] + red[1][1][o] + red[1][2][o] + red[1][3][o]);
    }
}

// sums (8 slots x 256) -> (a, b) fold:  h = relu(a*y + b)
__global__ __launch_bounds__(128) void mkab(const float* __restrict__ sums,
                                            const float* __restrict__ g,
                                            const float* __restrict__ be,
                                            float* __restrict__ ab, int C, float invP)
{
    int c = threadIdx.x;
    if (c >= C) return;
    float s = 0.f, q = 0.f;
#pragma unroll
    for (int k = 0; k < 8; ++k) { s += sums[k * 256 + c]; q += sums[k * 256 + 128 + c]; }
    float mu  = s * invP;
    float var = fmaf(-mu, mu, q * invP);
    float a   = g[c] / sqrtf(var + 1e-5f);
    ab[c]     = a;
    ab[C + c] = fmaf(-mu, a, be[c]);
}

// Elementwise fold: h = f16(relu(a*y + b)), NHWC, C = power of 2.
template <int C>
__global__ __launch_bounds__(256) void fold(const ushort* __restrict__ y,
                                            const float* __restrict__ ab,
                                            ushort* __restrict__ h)
{
    __shared__ float sa[C], sb[C];
    if (threadIdx.x < C) { sa[threadIdx.x] = ab[threadIdx.x]; sb[threadIdx.x] = ab[C + threadIdx.x]; }
    __syncthreads();
    int idx = blockIdx.x * 256 + threadIdx.x;
    half8 v;
    __builtin_memcpy(&v, y + (size_t)idx * 8, 16);
    int c0 = (idx * 8) & (C - 1);
    half8 o;
#pragma unroll
    for (int e = 0; e < 8; ++e) {
        float f = (float)v[e];
        o[e] = (_Float16)fmaxf(fmaf(sa[c0 + e], f, sb[c0 + e]), 0.f);
    }
    __builtin_memcpy(h + (size_t)idx * 8, &o, 16);
}

// Repack conv weights OIHW fp32 -> [oc][kh][kw][ic] f16.
template <int OC, int IC, int K>
__global__ __launch_bounds__(256) void repack(const float* __restrict__ w,
                                              ushort* __restrict__ wb)
{
    int i = blockIdx.x * 256 + threadIdx.x;
    int ic = i % IC;
    int r  = i / IC;
    int kw = r % K;  r /= K;
    int kh = r % K;
    int oc = r / K;
    wb[i] = f2h(w[((oc * IC + ic) * K + kh) * K + kw]);
}

// ---------------------------------------------------------------------------
// conv2: implicit GEMM, K=4 S=2 P=1, IC=16 OC=32, in (512,56,56,16) f16 NHWC.
// Chunk = (kh, kw-pair): k = kwoff*16 + ic (32 wide). Masked A loads (padding).
// Block: 4 waves x 32 m-rows = 128 m. M = 512*784 = 401408 = 3136*128.
// ---------------------------------------------------------------------------
__global__ __launch_bounds__(256, 2) void conv2_mfma(
    const ushort* __restrict__ hin, const ushort* __restrict__ wb,
    const float* __restrict__ bias, ushort* __restrict__ y,
    float* __restrict__ sums)
{
    const int lane = threadIdx.x & 63, wv = threadIdx.x >> 6;
    const int col = lane & 15, quad = lane >> 4;
    const int kwoff = quad >> 1;
    const int icoff = (quad & 1) * 8;
    const int mbase = blockIdx.x * 128 + wv * 32;

    int nb[2], ihb[2], iwb[2];
#pragma unroll
    for (int s = 0; s < 2; ++s) {
        int m = mbase + s * 16 + col;
        int n = m / 784, rem = m % 784;
        int oh = rem / 28, ow = rem % 28;
        nb[s]  = n * 50176 + icoff;   // n*IH*IW*IC + ic offset (halfs)
        ihb[s] = oh * 2 - 1;
        iwb[s] = ow * 2 - 1 + kwoff;
    }

    float bv[2];
#pragma unroll
    for (int t = 0; t < 2; ++t) bv[t] = bias[t * 16 + col];

    f32x4 acc[2][2];
#pragma unroll
    for (int s = 0; s < 2; ++s)
#pragma unroll
        for (int t = 0; t < 2; ++t) acc[s][t] = (f32x4){0.f, 0.f, 0.f, 0.f};

    const int wrow = col * 256 + icoff;  // oc*K*K*IC + icoff

#pragma unroll
    for (int kh = 0; kh < 4; ++kh) {
#pragma unroll
        for (int kwp = 0; kwp < 2; ++kwp) {
            half8 af[2];
#pragma unroll
            for (int s = 0; s < 2; ++s) {
                int ih = ihb[s] + kh;
                int iw = iwb[s] + kwp * 2;
                uint r0 = 0, r1 = 0, r2 = 0, r3 = 0;
                if ((uint)ih < 56u && (uint)iw < 56u) {
                    uint raw[4];
                    __builtin_memcpy(raw, hin + nb[s] + ih * 896 + iw * 16, 16);
                    r0 = raw[0]; r1 = raw[1]; r2 = raw[2]; r3 = raw[3];
                }
                uint raw2[4] = {r0, r1, r2, r3};
                __builtin_memcpy(&af[s], raw2, 16);
            }
            const int boff = (kh * 4 + kwp * 2 + kwoff) * 16;
#pragma unroll
            for (int t = 0; t < 2; ++t) {
                half8 bf;
                __builtin_memcpy(&bf, wb + wrow + t * 4096 + boff, 16);
#pragma unroll
                for (int s = 0; s < 2; ++s)
                    acc[s][t] = __builtin_amdgcn_mfma_f32_16x16x32_f16(af[s], bf, acc[s][t], 0, 0, 0);
            }
        }
    }

    // epilogue: bias, f16 store (NHWC), fused stats
    float ss[2] = {0.f, 0.f}, qq[2] = {0.f, 0.f};
#pragma unroll
    for (int s = 0; s < 2; ++s) {
        int m0 = mbase + s * 16 + quad * 4;
#pragma unroll
        for (int t = 0; t < 2; ++t) {
#pragma unroll
            for (int r = 0; r < 4; ++r) {
                float yv = acc[s][t][r] + bv[t];
                ss[t] += yv;
                qq[t] = fmaf(yv, yv, qq[t]);
                y[(size_t)(m0 + r) * 32 + t * 16 + col] = f2h(yv);
            }
        }
    }
    __shared__ float redS[4][32], redQ[4][32];
#pragma unroll
    for (int t = 0; t < 2; ++t) {
        float s = ss[t], q = qq[t];
        s += __shfl_xor(s, 16); s += __shfl_xor(s, 32);
        q += __shfl_xor(q, 16); q += __shfl_xor(q, 32);
        if (quad == 0) { redS[wv][t * 16 + col] = s; redQ[wv][t * 16 + col] = q; }
    }
    __syncthreads();
    int t0 = threadIdx.x;
    float* sl = sums + (blockIdx.x & 7) * 256;
    if (t0 < 32)
        atomicAdd(&sl[t0], redS[0][t0] + redS[1][t0] + redS[2][t0] + redS[3][t0]);
    else if (t0 >= 128 && t0 < 160) {
        int c = t0 - 128;
        atomicAdd(&sl[128 + c], redQ[0][c] + redQ[1][c] + redQ[2][c] + redQ[3][c]);
    }
}

// ---------------------------------------------------------------------------
// conv3/conv4: implicit GEMM, K=3 S=1 P=0 (no masks). NHWC f16 in/out.
// Block: 4 waves x 32 m-rows; wave does all OC tiles; chunks = K*K * IC/32.
// ---------------------------------------------------------------------------
template <int IC, int OC, int K, int IH, int IW, int OH, int OW>
__global__ __launch_bounds__(256, 2) void conv_np(
    const ushort* __restrict__ hin, const ushort* __restrict__ wb,
    const float* __restrict__ bias, ushort* __restrict__ y,
    float* __restrict__ sums)
{
    constexpr int NT = OC / 16, NC = IC / 32, KIC = K * K * IC;
    const int lane = threadIdx.x & 63, wv = threadIdx.x >> 6;
    const int col = lane & 15, quad = lane >> 4;
    const int mbase = blockIdx.x * 128 + wv * 32;

    int abase[2];
#pragma unroll
    for (int s = 0; s < 2; ++s) {
        int m = mbase + s * 16 + col;
        int n = m / (OH * OW), rem = m % (OH * OW);
        int oh = rem / OW, ow = rem % OW;
        abase[s] = ((n * IH + oh) * IW + ow) * IC + quad * 8;
    }

    float bv[NT];
#pragma unroll
    for (int t = 0; t < NT; ++t) bv[t] = bias[t * 16 + col];

    f32x4 acc[2][NT];
#pragma unroll
    for (int s = 0; s < 2; ++s)
#pragma unroll
        for (int t = 0; t < NT; ++t) acc[s][t] = (f32x4){0.f, 0.f, 0.f, 0.f};

    const int wrow = col * KIC + quad * 8;

#pragma unroll
    for (int kh = 0; kh < K; ++kh) {
#pragma unroll
        for (int kw = 0; kw < K; ++kw) {
#pragma unroll
            for (int c = 0; c < NC; ++c) {
                const int aoff = (kh * IW + kw) * IC + c * 32;
                half8 af[2];
#pragma unroll
                for (int s = 0; s < 2; ++s)
                    __builtin_memcpy(&af[s], hin + abase[s] + aoff, 16);
                const int kidx = (kh * K + kw) * IC + c * 32;
#pragma unroll
                for (int t = 0; t < NT; ++t) {
                    half8 bf;
                    __builtin_memcpy(&bf, wb + wrow + t * 16 * KIC + kidx, 16);
#pragma unroll
                    for (int s = 0; s < 2; ++s)
                        acc[s][t] = __builtin_amdgcn_mfma_f32_16x16x32_f16(af[s], bf, acc[s][t], 0, 0, 0);
                }
            }
        }
    }

    float ss[NT], qq[NT];
#pragma unroll
    for (int t = 0; t < NT; ++t) { ss[t] = 0.f; qq[t] = 0.f; }
#pragma unroll
    for (int s = 0; s < 2; ++s) {
        int m0 = mbase + s * 16 + quad * 4;
#pragma unroll
        for (int t = 0; t < NT; ++t) {
#pragma unroll
            for (int r = 0; r < 4; ++r) {
                float yv = acc[s][t][r] + bv[t];
                ss[t] += yv;
                qq[t] = fmaf(yv, yv, qq[t]);
                y[(size_t)(m0 + r) * OC + t * 16 + col] = f2h(yv);
            }
        }
    }
    __shared__ float redS[4][OC], redQ[4][OC];
#pragma unroll
    for (int t = 0; t < NT; ++t) {
        float s = ss[t], q = qq[t];
        s += __shfl_xor(s, 16); s += __shfl_xor(s, 32);
        q += __shfl_xor(q, 16); q += __shfl_xor(q, 32);
        if (quad == 0) { redS[wv][t * 16 + col] = s; redQ[wv][t * 16 + col] = q; }
    }
    __syncthreads();
    int t0 = threadIdx.x;
    float* sl = sums + (blockIdx.x & 7) * 256;
    if (t0 < OC)
        atomicAdd(&sl[t0], redS[0][t0] + redS[1][t0] + redS[2][t0] + redS[3][t0]);
    else if (t0 >= 128 && t0 < 128 + OC) {
        int c = t0 - 128;
        atomicAdd(&sl[128 + c], redQ[0][c] + redQ[1][c] + redQ[2][c] + redQ[3][c]);
    }
}

// Global average pool over y4 (512,24,24,128) f16 NHWC, BN4+ReLU applied.
__global__ __launch_bounds__(256) void pool(const ushort* __restrict__ y4,
                                            const float* __restrict__ ab,
                                            float* __restrict__ f)
{
    int n = blockIdx.x;
    int c = threadIdx.x & 127, ph = threadIdx.x >> 7;
    const ushort* p = y4 + (size_t)n * 73728 + c;
    float a = ab[c], b = ab[128 + c];
    float s = 0.f;
    for (int i = ph * 288; i < ph * 288 + 288; ++i) {
        _Float16 hv;
        __builtin_memcpy(&hv, p + i * 128, 2);
        s += fmaxf(fmaf(a, (float)hv, b), 0.f);
    }
    __shared__ float l[128];
    if (ph == 1) l[c] = s;
    __syncthreads();
    if (ph == 0) f[n * 128 + c] = (s + l[c]) * (1.f / 576.f);
}

// L2-normalize feature rows, emit f16.
__global__ __launch_bounds__(128) void fnorm(const float* __restrict__ f,
                                             ushort* __restrict__ fnh)
{
    int n = blockIdx.x, t = threadIdx.x;
    float v = f[n * 128 + t];
    float q = v * v;
    for (int off = 32; off; off >>= 1) q += __shfl_down(q, off);
    __shared__ float l[2];
    if ((t & 63) == 0) l[t >> 6] = q;
    __syncthreads();
    float inv = 1.f / fmaxf(sqrtf(l[0] + l[1]), 1e-12f);
    fnh[n * 128 + t] = f2h(v * inv);
}

// arc_w row inverse norms. One wave per row.
__global__ __launch_bounds__(256) void wnorm(const float* __restrict__ w,
                                             float* __restrict__ winv)
{
    int wv = threadIdx.x >> 6, lane = threadIdx.x & 63;
    int j = blockIdx.x * 4 + wv;
    const float* p = w + (size_t)j * 128;
    float v0 = p[lane], v1 = p[lane + 64];
    float q = fmaf(v0, v0, v1 * v1);
    for (int off = 32; off; off >>= 1) q += __shfl_down(q, off);
    if (lane == 0) winv[j] = 1.f / fmaxf(sqrtf(q), 1e-12f);
}

// ---------------------------------------------------------------------------
// Final GEMM: out[i][j] = 64 * (fn[i] . wn[j]), margin fix at j == gt[i].
// M=512, N=100000, K=128. f16 MFMA 16x16x32, fp32 accumulate.
// ---------------------------------------------------------------------------
__global__ __launch_bounds__(256) void arc_gemm(const ushort* __restrict__ fnh,
                                                const float* __restrict__ aw,
                                                const float* __restrict__ winv,
                                                const int* __restrict__ gt,
                                                float* __restrict__ out)
{
    const int lane = threadIdx.x & 63, wv = threadIdx.x >> 6;
    const int col = lane & 15, quad = lane >> 4;
    const int j = blockIdx.x * 64 + wv * 16 + col;
    const bool jvalid = (j < 100000);
    const int jc = jvalid ? j : 99999;

    const float wi = winv[jc];
    const float* wp = aw + (size_t)jc * 128 + quad * 8;
    half8 bfr[4];
#pragma unroll
    for (int s = 0; s < 4; ++s) {
        half8 t;
#pragma unroll
        for (int e = 0; e < 8; ++e) t[e] = (_Float16)(wp[s * 32 + e] * wi);
        bfr[s] = t;
    }

    const float cm = 0.87758256189037272f;  // cos(0.5)
    const float sm = 0.47942553860420301f;  // sin(0.5)

    for (int mt = 0; mt < 32; ++mt) {
        const ushort* ap = fnh + (size_t)(mt * 16 + col) * 128 + quad * 8;
        f32x4 acc = {0.f, 0.f, 0.f, 0.f};
#pragma unroll
        for (int s = 0; s < 4; ++s) {
            half8 af;
            __builtin_memcpy(&af, ap + s * 32, 16);
            acc = __builtin_amdgcn_mfma_f32_16x16x32_f16(af, bfr[s], acc, 0, 0, 0);
        }
#pragma unroll
        for (int r = 0; r < 4; ++r) {
            int row = mt * 16 + quad * 4 + r;
            float v = acc[r];
            float o = 64.f * v;
            if (gt[row] == j) {
                float t = fmaxf(1.f - v * v, 0.f);
                o = 64.f * fmaf(v, cm, -sqrtf(t) * sm);
            }
            if (jvalid) out[(size_t)row * 100000 + j] = o;
        }
    }
}

// ---------------------------------------------------------------------------
extern "C" void kernel_launch(void* const* d_in, const int* in_sizes, int n_in,
                              void* d_out, int out_size, void* d_ws, size_t ws_size,
                              hipStream_t stream)
{
    const float* x   = (const float*)d_in[0];
    const int*   gt  = (const int*)d_in[1];
    const float* w1  = (const float*)d_in[2];
    const float* b1  = (const float*)d_in[3];
    const float* g1  = (const float*)d_in[4];
    const float* be1 = (const float*)d_in[5];
    const float* w2  = (const float*)d_in[6];
    const float* b2  = (const float*)d_in[7];
    const float* g2  = (const float*)d_in[8];
    const float* be2 = (const float*)d_in[9];
    const float* w3  = (const float*)d_in[10];
    const float* b3  = (const float*)d_in[11];
    const float* g3  = (const float*)d_in[12];
    const float* be3 = (const float*)d_in[13];
    const float* w4  = (const float*)d_in[14];
    const float* b4  = (const float*)d_in[15];
    const float* g4  = (const float*)d_in[16];
    const float* be4 = (const float*)d_in[17];
    const float* aw  = (const float*)d_in[18];
    float* out = (float*)d_out;

    float* ws = (float*)d_ws;
    // arena1: y1(12.85M f) -> y2(6.42M) -> y3(11.08M) -> y4(18.87M floats)
    ushort* yb  = (ushort*)ws;
    // arena2: h1(12.85M f) -> h2(6.42M) -> h3(11.08M floats)
    ushort* hb  = (ushort*)(ws + 18874368);
    ushort* wb2 = (ushort*)(ws + 31719424);
    ushort* wb3 = (ushort*)(ws + 31723520);
    ushort* wb4 = (ushort*)(ws + 31732736);
    float* sums = ws + 31769600;   // 4 layers x 8 slots x 256
    float* ab   = ws + 31777792;   // 4 layers x 256
    float* fbuf = ws + 31778816;   // 512*128
    ushort* fnh = (ushort*)(ws + 31844352);  // 512*128 f16
    float* wiv  = ws + 31877120;   // 100,000

    hipMemsetAsync(sums, 0, 4 * 2048 * sizeof(float), stream);

    // weight repacks + wnorm (independent of conv chain)
    repack<32, 16, 4><<<32, 256, 0, stream>>>(w2, wb2);
    repack<64, 32, 3><<<72, 256, 0, stream>>>(w3, wb3);
    repack<128, 64, 3><<<288, 256, 0, stream>>>(w4, wb4);
    wnorm<<<25000, 256, 0, stream>>>(aw, wiv);

    // conv1: (512,1,112,112) fp32 -> y1 (512,56,56,16) f16 NHWC
    conv1_k<<<6272, 256, 0, stream>>>(x, w1, b1, yb, sums);
    mkab<<<1, 128, 0, stream>>>(sums, g1, be1, ab, 16, 1.f / 1605632.f);
    fold<16><<<12544, 256, 0, stream>>>(yb, ab, hb);

    // conv2 -> y2 (512,28,28,32) f16 NHWC
    conv2_mfma<<<3136, 256, 0, stream>>>(hb, wb2, b2, yb, sums + 2048);
    mkab<<<1, 128, 0, stream>>>(sums + 2048, g2, be2, ab + 256, 32, 1.f / 401408.f);
    fold<32><<<6272, 256, 0, stream>>>(yb, ab + 256, hb);

    // conv3 -> y3 (512,26,26,64) f16 NHWC
    conv_np<32, 64, 3, 28, 28, 26, 26><<<2704, 256, 0, stream>>>(hb, wb3, b3, yb, sums + 4096);
    mkab<<<1, 128, 0, stream>>>(sums + 4096, g3, be3, ab + 512, 64, 1.f / 346112.f);
    fold<64><<<10816, 256, 0, stream>>>(yb, ab + 512, hb);

    // conv4 -> y4 (512,24,24,128) f16 NHWC
    conv_np<64, 128, 3, 26, 26, 24, 24><<<2304, 256, 0, stream>>>(hb, wb4, b4, yb, sums + 6144);
    mkab<<<1, 128, 0, stream>>>(sums + 6144, g4, be4, ab + 768, 128, 1.f / 294912.f);

    // pool (applies BN4+ReLU) + feature normalize (f16)
    pool<<<512, 256, 0, stream>>>(yb, ab + 768, fbuf);
    fnorm<<<512, 128, 0, stream>>>(fbuf, fnh);

    // cosine logits + margin + scale
    arc_gemm<<<1563, 256, 0, stream>>>(fnh, aw, wiv, gt, out);
}